// Round 1
// baseline (574.438 us; speedup 1.0000x reference)
//
#include <hip/hip_runtime.h>

#define NEG_INF -1e30f

constexpr int BLANKC = 6624;
constexpr int NCLS   = 6625;
constexpr int TT     = 512;
constexpr int LL     = 32;
constexpr int NSLOT  = LL + 1;   // 33: slot 0 = blank, slot 1+j = label j
constexpr int BB     = 32;
constexpr int KPT    = TT / 64;  // 8 timesteps per lane

__device__ __forceinline__ float wave_allmax(float v) {
#pragma unroll
    for (int off = 32; off > 0; off >>= 1)
        v = fmaxf(v, __shfl_xor(v, off, 64));
    return v;
}
__device__ __forceinline__ float wave_allsum(float v) {
#pragma unroll
    for (int off = 32; off > 0; off >>= 1)
        v += __shfl_xor(v, off, 64);
    return v;
}

// Kernel A: for each (batch, slot) compute log_softmax over the TIME axis of
// the one class column this slot needs, write normalized column to ws.
// One wave per column; 4 waves per block.
__global__ __launch_bounds__(256) void ctc_colnorm(
    const float* __restrict__ x,        // [B, T, C]
    const int*   __restrict__ targets,  // [B, L]
    float*       __restrict__ cols)     // [B, NSLOT, T]
{
    const int wid  = blockIdx.x * 4 + (threadIdx.x >> 6);
    const int lane = threadIdx.x & 63;
    if (wid >= BB * NSLOT) return;
    const int b    = wid / NSLOT;
    const int slot = wid - b * NSLOT;
    const int c    = (slot == 0) ? BLANKC : targets[b * LL + slot - 1];

    const float* xb = x + (size_t)b * TT * NCLS + c;
    float v[KPT];
    float m = NEG_INF;
#pragma unroll
    for (int k = 0; k < KPT; ++k) {
        v[k] = xb[(size_t)(lane + 64 * k) * NCLS];
        m = fmaxf(m, v[k]);
    }
    m = wave_allmax(m);
    float s = 0.f;
#pragma unroll
    for (int k = 0; k < KPT; ++k) s += __expf(v[k] - m);
    s = wave_allsum(s);
    const float lse = m + __logf(s);

    float* cb = cols + (size_t)(b * NSLOT + slot) * TT;
#pragma unroll
    for (int k = 0; k < KPT; ++k) cb[lane + 64 * k] = v[k] - lse;
}

// Kernel B: alpha recursion. One wave per batch; lane = state s (0..63),
// state 64 tracked as a redundant scalar on all lanes (it is a sink: only
// alpha[64], alpha[63], alpha[62] feed it, and allow_skip[64]=false since
// ext[64]=blank).
__global__ __launch_bounds__(64) void ctc_alpha(
    const float* __restrict__ cols,     // [B, NSLOT, T]
    const int*   __restrict__ targets,  // [B, L]
    const int*   __restrict__ input_lengths,
    const int*   __restrict__ target_lengths,
    float*       __restrict__ part)     // [B] per-batch loss
{
    const int b = blockIdx.x;
    const int s = threadIdx.x;          // 0..63
    const int j = s >> 1;               // label index when s is odd
    const bool odd = (s & 1) != 0;

    // allow_skip[s] = (ext[s] != blank) && (ext[s] != ext[s-2])
    const int ext_s = odd ? targets[b * LL + j] : BLANKC;
    bool allow;
    if (!odd)            allow = false;
    else if (s == 1)     allow = (ext_s != BLANKC);   // ext[-1] is padded blank
    else                 allow = (ext_s != BLANKC) && (ext_s != targets[b * LL + j - 1]);

    const float* bcol = cols + (size_t)b * NSLOT * TT;             // blank column
    const float* ecol = bcol + (odd ? (size_t)(1 + j) * TT : (size_t)0);

    const int ilen = input_lengths[b];
    const int tlen = target_lengths[b];

    float alpha = NEG_INF;
    if (s == 0) alpha = bcol[0];        // emit(t=0, blank)
    if (s == 1) alpha = bcol[TT];       // emit(t=0, label 0)
    float a64 = NEG_INF;

    for (int t = 1; t < TT; ++t) {
        const float e  = ecol[t];       // address independent of recurrence -> pipelines
        const float eb = bcol[t];
        float am1 = __shfl_up(alpha, 1, 64);
        float am2 = __shfl_up(alpha, 2, 64);
        const float a63 = __shfl(alpha, 63, 64);
        if (s == 0) am1 = NEG_INF;
        if (s < 2 || !allow) am2 = NEG_INF;

        // 3-way logsumexp (all args <= m, so exp args <= 0 -> no overflow)
        const float m  = fmaxf(fmaxf(alpha, am1), am2);
        const float na = m + __logf(__expf(alpha - m) + __expf(am1 - m) + __expf(am2 - m)) + e;
        // state 64: 2-way (allow_skip false)
        const float m2   = fmaxf(a64, a63);
        const float na64 = m2 + __logf(__expf(a64 - m2) + __expf(a63 - m2)) + eb;

        const bool live = (t < ilen);   // freeze past input_length
        alpha = live ? na   : alpha;
        a64   = live ? na64 : a64;
    }

    const int idx1 = 2 * tlen;                    // final blank (may be 64)
    const int idx2 = max(2 * tlen - 1, 0);        // final label (<= 63)
    const float l1 = (idx1 >= 64) ? a64 : __shfl(alpha, idx1, 64);
    const float l2 = (idx2 >= 64) ? a64 : __shfl(alpha, idx2, 64);
    const float mm = fmaxf(l1, l2);
    float loss = -(mm + __logf(__expf(l1 - mm) + __expf(l2 - mm)));
    if (loss > 1e20f) loss = 0.f;                 // zero_infinity
    loss /= (float)max(tlen, 1);
    if (s == 0) part[b] = loss;
}

// Kernel C: mean over batch into d_out (d_out is poisoned each call -> must write).
__global__ __launch_bounds__(64) void ctc_reduce(
    const float* __restrict__ part, float* __restrict__ out)
{
    const int lane = threadIdx.x;
    float v = (lane < BB) ? part[lane] : 0.f;
#pragma unroll
    for (int off = 32; off > 0; off >>= 1) v += __shfl_xor(v, off, 64);
    if (lane == 0) out[0] = v / (float)BB;
}

extern "C" void kernel_launch(void* const* d_in, const int* in_sizes, int n_in,
                              void* d_out, int out_size, void* d_ws, size_t ws_size,
                              hipStream_t stream) {
    const float* lp      = (const float*)d_in[0];   // [B, T, C] fp32
    const int*   targets = (const int*)d_in[1];     // [B, L]
    const int*   ilen    = (const int*)d_in[2];     // [B]
    const int*   tlen    = (const int*)d_in[3];     // [B]
    float* out = (float*)d_out;

    // ws layout: [0, COLS_BYTES) normalized columns, then per-batch losses
    constexpr size_t COLS_ELEMS = (size_t)BB * NSLOT * TT;          // 541,696 floats
    float* cols = (float*)d_ws;
    float* part = (float*)d_ws + COLS_ELEMS;

    const int gridA = (BB * NSLOT + 3) / 4;   // 4 waves (columns) per block
    ctc_colnorm<<<gridA, 256, 0, stream>>>(lp, targets, cols);
    ctc_alpha<<<BB, 64, 0, stream>>>(cols, targets, ilen, tlen, part);
    ctc_reduce<<<1, 64, 0, stream>>>(part, out);
}